// Round 2
// baseline (250.717 us; speedup 1.0000x reference)
//
#include <hip/hip_runtime.h>
#include <math.h>

#define D 128
#define D2 64   // float2 per row

__global__ void zero_kernel(int* __restrict__ p, int n) {
    int i = blockIdx.x * blockDim.x + threadIdx.x;
    if (i < n) p[i] = 0;
}

// ---- degree count over dst (edge_index delivered as int32) ----
__global__ void deg_kernel(const int* __restrict__ ei, int E, int* __restrict__ cnt) {
    int e = blockIdx.x * blockDim.x + threadIdx.x;
    if (e < E) atomicAdd(&cnt[ei[E + e]], 1);
}

// ---- single-block scan: offsets (exclusive), deg_isqrt (with self loop), zero cursor ----
__global__ void scan_kernel(const int* __restrict__ cnt, float* __restrict__ disq,
                            int* __restrict__ offs, int* __restrict__ cursor, int n) {
    __shared__ int part[1024];
    int t = threadIdx.x;
    int chunk = (n + 1023) >> 10;
    int c0 = t * chunk, c1 = min(c0 + chunk, n);
    int s = 0;
    for (int i = c0; i < c1; ++i) s += cnt[i];
    part[t] = s;
    __syncthreads();
    for (int d = 1; d < 1024; d <<= 1) {
        int u = (t >= d) ? part[t - d] : 0;
        __syncthreads();
        part[t] += u;
        __syncthreads();
    }
    int run = part[t] - s;   // exclusive base
    for (int i = c0; i < c1; ++i) {
        offs[i] = run;
        int c = cnt[i];
        disq[i] = rsqrtf((float)(c + 1));   // +1 self loop -> deg >= 1 always
        cursor[i] = 0;
        run += c;
    }
    if (c1 == n && c0 <= n) offs[n] = run;
}

// ---- scatter edges into CSR (by dst, storing src) ----
__global__ void csr_fill(const int* __restrict__ ei, int E,
                         const int* __restrict__ offs, int* __restrict__ cursor,
                         int* __restrict__ csr) {
    int e = blockIdx.x * blockDim.x + threadIdx.x;
    if (e < E) {
        int s = ei[e];
        int d = ei[E + e];
        int p = atomicAdd(&cursor[d], 1);
        csr[offs[d] + p] = s;
    }
}

// ---- g = (x @ W) * deg_isqrt[row]  (W staged in LDS, x via wave-uniform scalar loads) ----
__global__ __launch_bounds__(256) void gemm_scale(const float* __restrict__ x,
                                                  const float* __restrict__ W,
                                                  const float* __restrict__ disq,
                                                  float* __restrict__ g, int n) {
    __shared__ float Ws[D * D];
    const float4* W4 = (const float4*)W;
    float4* Ws4 = (float4*)Ws;
#pragma unroll
    for (int i = 0; i < (D * D / 4) / 256; ++i)
        Ws4[i * 256 + threadIdx.x] = W4[i * 256 + threadIdx.x];
    __syncthreads();

    int j = threadIdx.x & (D - 1);
    int half = threadIdx.x >> 7;          // wave-uniform
    int row0 = blockIdx.x * 32 + half * 16;
    if (row0 > n - 16) row0 = n - 16;     // tail: duplicate rows write identical values
    row0 = __builtin_amdgcn_readfirstlane(row0);
    const float* xrow = x + (size_t)row0 * D;

    float acc[16];
#pragma unroll
    for (int r = 0; r < 16; ++r) acc[r] = 0.f;

#pragma unroll 4
    for (int k = 0; k < D; ++k) {
        float wv = Ws[k * D + j];
#pragma unroll
        for (int r = 0; r < 16; ++r) acc[r] = fmaf(xrow[r * D + k], wv, acc[r]);
    }
#pragma unroll
    for (int r = 0; r < 16; ++r) {
        int row = row0 + r;
        g[(size_t)row * D + j] = disq[row] * acc[r];
    }
}

// ---- per-node aggregate (+self loop) + bias, then fused PairNorm + skip + GELU ----
// mode 0: write xout = gelu(pn(conv)+prev), pout = pn(conv)+prev
// mode 1: write out3 = conv only (final layer)
__global__ void agg_kernel(const float* __restrict__ g, const float* __restrict__ disq,
                           const int* __restrict__ offs, const int* __restrict__ csr,
                           const float* __restrict__ bias, const float* __restrict__ prev,
                           float* __restrict__ xout, float* __restrict__ pout,
                           float* __restrict__ out3, int mode) {
    int i = blockIdx.x;
    int l = threadIdx.x;                 // 0..63, each lane owns 2 floats
    const float2* g2 = (const float2*)g;

    float2 acc = g2[(size_t)i * D2 + l]; // self loop term
    int e = offs[i], e1 = offs[i + 1];
    for (; e + 4 <= e1; e += 4) {        // 4 indices in flight
        int s0 = csr[e], s1 = csr[e + 1], s2 = csr[e + 2], s3 = csr[e + 3];
        float2 v0 = g2[(size_t)s0 * D2 + l];
        float2 v1 = g2[(size_t)s1 * D2 + l];
        float2 v2 = g2[(size_t)s2 * D2 + l];
        float2 v3 = g2[(size_t)s3 * D2 + l];
        acc.x += v0.x + v1.x + v2.x + v3.x;
        acc.y += v0.y + v1.y + v2.y + v3.y;
    }
    for (; e < e1; ++e) {
        int s = csr[e];
        float2 v = g2[(size_t)s * D2 + l];
        acc.x += v.x; acc.y += v.y;
    }

    float di = disq[i];
    float2 bv = ((const float2*)bias)[l];
    float ox = fmaf(di, acc.x, bv.x);
    float oy = fmaf(di, acc.y, bv.y);

    if (mode) {
        ((float2*)out3)[(size_t)i * D2 + l] = make_float2(ox, oy);
        return;
    }

    // PairNorm 'PN': row / (||row||_2 + eps)
    float ss = ox * ox + oy * oy;
#pragma unroll
    for (int m = 1; m < 64; m <<= 1) ss += __shfl_xor(ss, m);
    float inv = 1.0f / (sqrtf(ss) + 1e-8f);

    float2 pv = ((const float2*)prev)[(size_t)i * D2 + l];
    float nx = fmaf(ox, inv, pv.x);
    float ny = fmaf(oy, inv, pv.y);
    ((float2*)pout)[(size_t)i * D2 + l] = make_float2(nx, ny);

    const float ISQ2 = 0.70710678118654752440f;
    float gx = 0.5f * nx * (1.0f + erff(nx * ISQ2));
    float gy = 0.5f * ny * (1.0f + erff(ny * ISQ2));
    ((float2*)xout)[(size_t)i * D2 + l] = make_float2(gx, gy);
}

extern "C" void kernel_launch(void* const* d_in, const int* in_sizes, int n_in,
                              void* d_out, int out_size, void* d_ws, size_t ws_size,
                              hipStream_t stream) {
    const float* x  = (const float*)d_in[0];
    const int*   ei = (const int*)d_in[1];          // int32 per harness contract
    const float* W1 = (const float*)d_in[2];
    const float* b1 = (const float*)d_in[3];
    const float* W2 = (const float*)d_in[4];
    const float* b2 = (const float*)d_in[5];
    const float* W3 = (const float*)d_in[6];
    const float* b3 = (const float*)d_in[7];
    int n = in_sizes[0] / D;
    int E = in_sizes[1] / 2;

    char* p = (char*)d_ws;
    auto carve = [&](size_t bytes) {
        char* q = p;
        p += (bytes + 511) & ~(size_t)511;
        return q;
    };
    int*   cnt    = (int*)carve((size_t)n * 4);
    int*   cursor = (int*)carve((size_t)n * 4);
    int*   offs   = (int*)carve((size_t)(n + 1) * 4);
    float* disq   = (float*)carve((size_t)n * 4);
    int*   csr    = (int*)carve((size_t)E * 4);
    float* g      = (float*)carve((size_t)n * D * 4);
    float* xa     = (float*)carve((size_t)n * D * 4);
    float* pa     = (float*)d_out;   // alias: layer-3 agg never reads prev; final write covers d_out

    zero_kernel<<<(n + 255) / 256, 256, 0, stream>>>(cnt, n);
    int eb = (E + 255) / 256;
    deg_kernel<<<eb, 256, 0, stream>>>(ei, E, cnt);
    scan_kernel<<<1, 1024, 0, stream>>>(cnt, disq, offs, cursor, n);
    csr_fill<<<eb, 256, 0, stream>>>(ei, E, offs, cursor, csr);

    int gb = (n + 31) / 32;
    float* out = (float*)d_out;

    gemm_scale<<<gb, 256, 0, stream>>>(x, W1, disq, g, n);
    agg_kernel<<<n, 64, 0, stream>>>(g, disq, offs, csr, b1, x, xa, pa, nullptr, 0);

    gemm_scale<<<gb, 256, 0, stream>>>(xa, W2, disq, g, n);
    agg_kernel<<<n, 64, 0, stream>>>(g, disq, offs, csr, b2, pa, xa, pa, nullptr, 0);

    gemm_scale<<<gb, 256, 0, stream>>>(xa, W3, disq, g, n);
    agg_kernel<<<n, 64, 0, stream>>>(g, disq, offs, csr, b3, nullptr, nullptr, nullptr, out, 1);
}